// Round 1
// baseline (96.608 us; speedup 1.0000x reference)
//
#include <hip/hip_runtime.h>

// Sizes (fixed by the reference)
#define Bq 32
#define Gq 16
#define Oq 256
#define Nq 88
#define Tq 256

typedef short bf16x8 __attribute__((ext_vector_type(8)));   // 8 bf16 in 4 VGPRs
typedef float f32x4 __attribute__((ext_vector_type(4)));

static __device__ __forceinline__ short f2bf(float f) {
    return __builtin_bit_cast(short, (__bf16)f);  // RNE convert, bits as short
}

// out[b,n,o] = sum_{g,t} x[b,n,t] * y[b,g] * w[g,o,n,t] * mask[o,t] + bias[o]
// Per block: one (n, 16-wide o-tile). 4 waves split K by g (4 g's each).
// MFMA 16x16x32 bf16: A = x*y (M=b rows), B = w*mask (N=o cols), fp32 acc.
// k-permutation sigma inside each K=32 window: frag position (hi,j) holds
// t = t0 + (j<4 ? hi*4+j : 16+hi*4+(j-4))  -> every dwordx4 load is a
// contiguous 64B-aligned 64B chunk per row-stream. Same sigma on A and B.
__global__ __launch_bounds__(256, 4)
void mlm_mfma(const float* __restrict__ x, const float* __restrict__ y,
              const float* __restrict__ w, const float* __restrict__ mask,
              const float* __restrict__ bias, float* __restrict__ out) {
    const int unit = blockIdx.x;
    const int n  = unit >> 4;          // 0..87
    const int o0 = (unit & 15) << 4;   // o-tile base
    const int tid  = threadIdx.x;
    const int wave = tid >> 6;         // 0..3  -> g in [4*wave, 4*wave+3]
    const int lane = tid & 63;
    const int lo = lane & 15;          // A row (b) / B col (o) / C col
    const int hi = lane >> 4;          // k-group 0..3

    __shared__ float red[4][32][16];   // partial C per wave

    f32x4 acc0 = {0.f, 0.f, 0.f, 0.f};  // b = 0..15 rows
    f32x4 acc1 = {0.f, 0.f, 0.f, 0.f};  // b = 16..31 rows

    const float* xp0 = x + ((size_t)lo * Nq + n) * Tq;          // b = lo
    const float* xp1 = x + ((size_t)(lo + 16) * Nq + n) * Tq;   // b = lo+16
    const float* mp  = mask + (size_t)(o0 + lo) * Tq;           // o = o0+lo
    const float* wp  = w + ((size_t)((wave * 4) * Oq + (o0 + lo)) * Nq + n) * Tq;
    const size_t GS = (size_t)Oq * Nq * Tq;                     // g-stride

    float ya[4], yb[4];
#pragma unroll
    for (int gi = 0; gi < 4; ++gi) {
        ya[gi] = y[lo * Gq + wave * 4 + gi];
        yb[gi] = y[(lo + 16) * Gq + wave * 4 + gi];
    }

    for (int t0 = 0; t0 < Tq; t0 += 32) {
        const int ta = t0 + hi * 4;
        const int tb = ta + 16;
        // x and mask chunks shared across the 4 g's of this wave
        f32x4 xa0 = *(const f32x4*)(xp0 + ta);
        f32x4 xb0 = *(const f32x4*)(xp0 + tb);
        f32x4 xa1 = *(const f32x4*)(xp1 + ta);
        f32x4 xb1 = *(const f32x4*)(xp1 + tb);
        f32x4 ma  = *(const f32x4*)(mp + ta);
        f32x4 mb  = *(const f32x4*)(mp + tb);
#pragma unroll
        for (int gi = 0; gi < 4; ++gi) {
            const float* wgp = wp + (size_t)gi * GS;
            f32x4 wa = *(const f32x4*)(wgp + ta);
            f32x4 wb = *(const f32x4*)(wgp + tb);
            bf16x8 af0, af1, bfr;
#pragma unroll
            for (int j = 0; j < 4; ++j) {
                bfr[j]     = f2bf(wa[j] * ma[j]);
                bfr[j + 4] = f2bf(wb[j] * mb[j]);
                af0[j]     = f2bf(xa0[j] * ya[gi]);
                af0[j + 4] = f2bf(xb0[j] * ya[gi]);
                af1[j]     = f2bf(xa1[j] * yb[gi]);
                af1[j + 4] = f2bf(xb1[j] * yb[gi]);
            }
            acc0 = __builtin_amdgcn_mfma_f32_16x16x32_bf16(af0, bfr, acc0, 0, 0, 0);
            acc1 = __builtin_amdgcn_mfma_f32_16x16x32_bf16(af1, bfr, acc1, 0, 0, 0);
        }
    }

    // C/D layout (m89-verified): col = lane&15, row = (lane>>4)*4 + reg
#pragma unroll
    for (int i = 0; i < 4; ++i) {
        red[wave][hi * 4 + i][lo]      = acc0[i];
        red[wave][16 + hi * 4 + i][lo] = acc1[i];
    }
    __syncthreads();

    // 512 outputs (32 b x 16 o), 256 threads -> 2 each; sum 4 wave-partials
#pragma unroll
    for (int s = 0; s < 2; ++s) {
        const int idx = tid + s * 256;
        const int b  = idx >> 4;
        const int oo = idx & 15;
        const float v = red[0][b][oo] + red[1][b][oo] + red[2][b][oo] + red[3][b][oo]
                      + bias[o0 + oo];
        out[((size_t)b * Nq + n) * Oq + o0 + oo] = v;
    }
}

extern "C" void kernel_launch(void* const* d_in, const int* in_sizes, int n_in,
                              void* d_out, int out_size, void* d_ws, size_t ws_size,
                              hipStream_t stream) {
    const float* x    = (const float*)d_in[0];
    const float* y    = (const float*)d_in[1];
    const float* w    = (const float*)d_in[2];
    const float* mask = (const float*)d_in[3];
    const float* bias = (const float*)d_in[4];
    float* out = (float*)d_out;

    dim3 grid(Nq * (Oq / 16));  // 88 n-slices * 16 o-tiles = 1408 blocks
    dim3 block(256);
    hipLaunchKernelGGL(mlm_mfma, grid, block, 0, stream, x, y, w, mask, bias, out);
}

// Round 2
// 75.202 us; speedup vs baseline: 1.2846x; 1.2846x over previous
//
#include <hip/hip_runtime.h>

// Sizes (fixed by the reference)
#define Bq 32
#define Gq 16
#define Oq 256
#define Nq 88
#define Tq 256

typedef short bf16x8 __attribute__((ext_vector_type(8)));   // 8 bf16 in 4 VGPRs
typedef float f32x4 __attribute__((ext_vector_type(4)));

static __device__ __forceinline__ short f2bf(float f) {
    return __builtin_bit_cast(short, (__bf16)f);  // RNE convert, bits as short
}

// Async global->LDS, 16B per lane. Dest = wave-uniform base + lane*16 (linear).
// Source is per-lane -> swizzle is applied on the GLOBAL side (rule 21).
static __device__ __forceinline__ void gld_lds16(const float* src, float* lds_dst) {
    __builtin_amdgcn_global_load_lds(
        (const __attribute__((address_space(1))) void*)src,
        (__attribute__((address_space(3))) void*)lds_dst, 16, 0, 0);
}

// out[b,n,o] = sum_{g,t} x[b,n,t] * y[b,g] * w[g,o,n,t] * mask[o,t] + bias[o]
//
// Block = (n, 16-wide o-tile). 4 waves split t (64 t's each); g processed
// sequentially with a double-buffered LDS slab of w[g, o0:o0+16, n, :]
// (16 rows x 1KB), staged via global_load_lds as FULL 1KB contiguous bursts
// (one wave-instruction per row). A = x (bf16, no scaling) built once and
// reused across all g; y[b,g] applied per-g to the f32 MFMA partial.
// LDS row swizzle: chunk_phys = chunk_log ^ (row & 7), applied on the global
// source at staging and on the ds_read address (XOR involution).
__global__ __launch_bounds__(256, 4)
void mlm_mfma2(const float* __restrict__ x, const float* __restrict__ y,
               const float* __restrict__ w, const float* __restrict__ mask,
               const float* __restrict__ bias, float* __restrict__ out) {
    __shared__ float wbuf[2][4096];   // 2 x 16KB: [16 rows(o)][64 chunks x 4 floats]
    __shared__ float y_lds[512];      // y[b][g] row-major

    const int n  = blockIdx.x >> 4;          // 0..87
    const int o0 = (blockIdx.x & 15) << 4;   // o-tile base
    const int tid  = threadIdx.x;
    const int wv   = tid >> 6;        // 0..3 -> t-range [wv*64, wv*64+64)
    const int lane = tid & 63;
    const int lo = lane & 15;         // A row-slot / B col (o) / C col
    const int hi = lane >> 4;         // k-group 0..3
    const int sr = lo & 7;            // read-side swizzle key (row = lo)

    // stage y into LDS
    y_lds[tid]       = y[tid];
    y_lds[tid + 256] = y[tid + 256];

    // A fragments (x -> bf16) and mask chunks: built once, live for all 16 g.
    // k-perm sigma: frag elem (hi,j): j<4 -> t = t0+hi*4+j ; j>=4 -> t0+16+hi*4+(j-4)
    bf16x8 afrag[2][2];               // [window W][b-half]
    f32x4 mka[2], mkb[2];
    const int tbase = wv * 64;
#pragma unroll
    for (int W = 0; W < 2; ++W) {
        const int ta = tbase + W * 32 + hi * 4;
        const int tb = ta + 16;
        f32x4 xa0 = *(const f32x4*)(x + ((size_t)lo * Nq + n) * Tq + ta);
        f32x4 xb0 = *(const f32x4*)(x + ((size_t)lo * Nq + n) * Tq + tb);
        f32x4 xa1 = *(const f32x4*)(x + ((size_t)(lo + 16) * Nq + n) * Tq + ta);
        f32x4 xb1 = *(const f32x4*)(x + ((size_t)(lo + 16) * Nq + n) * Tq + tb);
        mka[W] = *(const f32x4*)(mask + (size_t)(o0 + lo) * Tq + ta);
        mkb[W] = *(const f32x4*)(mask + (size_t)(o0 + lo) * Tq + tb);
#pragma unroll
        for (int j = 0; j < 4; ++j) {
            afrag[W][0][j]     = f2bf(xa0[j]);
            afrag[W][0][j + 4] = f2bf(xb0[j]);
            afrag[W][1][j]     = f2bf(xa1[j]);
            afrag[W][1][j + 4] = f2bf(xb1[j]);
        }
    }

    // weight row base pointers (g = 0) for this wave's 4 staging rows
    const size_t GS = (size_t)Oq * Nq * Tq;   // g-stride in floats
    const float* wrow[4];
#pragma unroll
    for (int q = 0; q < 4; ++q) {
        const int r = wv * 4 + q;
        wrow[q] = w + ((size_t)(o0 + r) * Nq + n) * Tq;
    }

    // stage g = 0 into buf 0 (one full 1KB row per wave-instruction)
#pragma unroll
    for (int q = 0; q < 4; ++q) {
        const int r = wv * 4 + q;
        gld_lds16(wrow[q] + ((lane ^ (r & 7)) << 2), &wbuf[0][r * 256]);
    }
    asm volatile("s_waitcnt vmcnt(0)" ::: "memory");
    __syncthreads();

    f32x4 facc0 = {0.f, 0.f, 0.f, 0.f};   // b = 0..15 rows (y-weighted)
    f32x4 facc1 = {0.f, 0.f, 0.f, 0.f};   // b = 16..31 rows

    for (int g = 0; g < 16; ++g) {
        const int cb = g & 1;
        // prefetch next g's slab into the other buffer
        if (g < 15) {
#pragma unroll
            for (int q = 0; q < 4; ++q) {
                const int r = wv * 4 + q;
                gld_lds16(wrow[q] + (size_t)(g + 1) * GS + ((lane ^ (r & 7)) << 2),
                          &wbuf[cb ^ 1][r * 256]);
            }
        }

        f32x4 acc0 = {0.f, 0.f, 0.f, 0.f};
        f32x4 acc1 = {0.f, 0.f, 0.f, 0.f};
#pragma unroll
        for (int W = 0; W < 2; ++W) {
            const int c0 = wv * 16 + W * 8 + hi;   // global chunk of wa
            f32x4 wa4 = *(const f32x4*)&wbuf[cb][lo * 256 + ((c0 ^ sr) << 2)];
            f32x4 wb4 = *(const f32x4*)&wbuf[cb][lo * 256 + (((c0 + 4) ^ sr) << 2)];
            bf16x8 bfr;
#pragma unroll
            for (int j = 0; j < 4; ++j) {
                bfr[j]     = f2bf(wa4[j] * mka[W][j]);
                bfr[j + 4] = f2bf(wb4[j] * mkb[W][j]);
            }
            acc0 = __builtin_amdgcn_mfma_f32_16x16x32_bf16(afrag[W][0], bfr, acc0, 0, 0, 0);
            acc1 = __builtin_amdgcn_mfma_f32_16x16x32_bf16(afrag[W][1], bfr, acc1, 0, 0, 0);
        }

        // apply y[b,g] to this g's f32 partial (C row b = half*16 + hi*4 + i)
#pragma unroll
        for (int i = 0; i < 4; ++i) {
            facc0[i] += y_lds[(hi * 4 + i) * Gq + g] * acc0[i];
            facc1[i] += y_lds[(16 + hi * 4 + i) * Gq + g] * acc1[i];
        }

        asm volatile("s_waitcnt vmcnt(0)" ::: "memory");
        __syncthreads();
    }

    // cross-wave (t-split) reduction; reuse wbuf[0] as red[4][32][16]
    float (*red)[32][16] = (float (*)[32][16]) & wbuf[0][0];
#pragma unroll
    for (int i = 0; i < 4; ++i) {
        red[wv][hi * 4 + i][lo]      = facc0[i];
        red[wv][16 + hi * 4 + i][lo] = facc1[i];
    }
    __syncthreads();

#pragma unroll
    for (int s = 0; s < 2; ++s) {
        const int idx = tid + s * 256;
        const int b  = idx >> 4;
        const int oo = idx & 15;
        const float v = red[0][b][oo] + red[1][b][oo] + red[2][b][oo] + red[3][b][oo]
                      + bias[o0 + oo];
        out[((size_t)b * Nq + n) * Oq + o0 + oo] = v;
    }
}

extern "C" void kernel_launch(void* const* d_in, const int* in_sizes, int n_in,
                              void* d_out, int out_size, void* d_ws, size_t ws_size,
                              hipStream_t stream) {
    const float* x    = (const float*)d_in[0];
    const float* y    = (const float*)d_in[1];
    const float* w    = (const float*)d_in[2];
    const float* mask = (const float*)d_in[3];
    const float* bias = (const float*)d_in[4];
    float* out = (float*)d_out;

    dim3 grid(Nq * (Oq / 16));  // 88 n-slices * 16 o-tiles = 1408 blocks
    dim3 block(256);
    hipLaunchKernelGGL(mlm_mfma2, grid, block, 0, stream, x, y, w, mask, bias, out);
}